// Round 5
// baseline (15134.186 us; speedup 1.0000x reference)
//
#include <hip/hip_runtime.h>
#include <math.h>

// ---------------------------------------------------------------------------
// LinTransformer, split-bf16 (bf16x3) MFMA implementation, round 5
// (identical to round-4 submission, which never got benched).
//   - XCD-chunked block swizzle (T1)
//   - global_load_lds width-16 staging, XOR slot-swizzled LDS (T2/T21)
//   - LDS-staged coalesced epilogue (fixes 9-18x write amplification)
//   - attn-out (numer/den + residual) fused into intra-chunk gemm
// Every GEMM is NT (C = A * B^T) on 16x16x32 bf16 MFMA with fp32 accum:
//   A = Ah + Al, B = Bh + Bl;  C ~= Ah*Bh + Ah*Bl + Al*Bh.
// ---------------------------------------------------------------------------

#define SEQ    2048
#define NB     16
#define DIO    512
#define DM     1024
#define NLAYER 3
#define ROWS   (SEQ * NB)      // 32768
#define LC     64
#define NCH    (SEQ / LC)      // 32
#define RC     (LC * NB)       // 1024

typedef __attribute__((ext_vector_type(8))) short bf16x8;
typedef __attribute__((ext_vector_type(4))) float f32x4;

#if defined(__has_builtin)
#if __has_builtin(__builtin_amdgcn_global_load_lds)
#define HAS_GLL 1
#endif
#endif

__device__ __forceinline__ ushort f2bf(float f) {
    unsigned u = __float_as_uint(f);
    return (ushort)((u + 0x7fffu + ((u >> 16) & 1u)) >> 16);
}
__device__ __forceinline__ float bf2f(ushort h) {
    return __uint_as_float((unsigned)h << 16);
}
__device__ __forceinline__ void split2(float f, ushort& h, ushort& l) {
    h = f2bf(f);
    l = f2bf(f - bf2f(h));
}
__device__ __forceinline__ float rc1(ushort h, ushort l) {
    return bf2f(h) + bf2f(l);
}
// bank-swizzled LDS indices for the staged epilogue (16B-granule XOR)
__device__ __forceinline__ int sidx16(int r, int c) {   // ushort image 128x128
    return r * 128 + ((((c >> 3) ^ (r & 15)) & 15) << 3) + (c & 7);
}
__device__ __forceinline__ int sidxf(int r, int c) {    // float image 64x128
    return r * 128 + ((((c >> 2) ^ (r & 7)) & 31) << 2) + (c & 3);
}

// ---------------------------------------------------------------------------
// mgemm: C[m,n] = epilogue( sum_k A[m,k]*B[n,k] ), 128x128 tile, 4 waves,
// wave quadrant 64x64 = 4x4 fragments of 16x16, BK=32.
// AOUT: v = (acc + Cf)/den + Rf, planes only (fused linear-attn output).
// ---------------------------------------------------------------------------
template <int ACT, bool PE, bool CAUSAL, bool KLIM, bool AOUT>
__global__ __launch_bounds__(256) void mgemm(
    const ushort* __restrict__ Ah, const ushort* __restrict__ Al,
    const ushort* __restrict__ Bh, const ushort* __restrict__ Bl,
    const float* __restrict__ bias,
    float* __restrict__ Cf, ushort* __restrict__ Ch, ushort* __restrict__ Cl,
    const float* __restrict__ Rf, const float* __restrict__ den, int accf,
    int M, int N, int K, long sA, long sB, long sC)
{
    const int cz = blockIdx.z;
    Ah += (long)cz * sA; Al += (long)cz * sA;
    Bh += (long)cz * sB; Bl += (long)cz * sB;
    const long cbase = (long)cz * sC;

    // XCD-chunked bijective swizzle (all grids have nwg % 8 == 0)
    const int nx = gridDim.x;
    const int lin = blockIdx.y * nx + blockIdx.x;
    const int chunkpx = (nx * gridDim.y) >> 3;
    const int nl = (lin & 7) * chunkpx + (lin >> 3);
    const int bm = nl / nx, bn = nl % nx;

    if (CAUSAL && bn > bm) return;          // strictly-upper tiles: never read

    const int tid = threadIdx.x;
    const int lane = tid & 63;
    const int wv = tid >> 6;                 // wave 0..3
    const int wr = wv >> 1, wc = wv & 1;     // 2x2 wave grid

    __shared__ __align__(16) ushort lds[4][4096];   // 32 KB

    const ushort* gsrc = (wv == 0) ? Ah : (wv == 1) ? Al : (wv == 2) ? Bh : Bl;
    const long rowbase = (long)((wv < 2 ? bm : bn) * 128);

    const int kmax = KLIM ? (((bm + 1) * 128 < K) ? (bm + 1) * 128 : K) : K;

    // per-lane pre-inverse-swizzled global source pointers (8 issues/plane)
    const ushort* gp[8];
    {
        const int lr = lane >> 2, sst = lane & 3;
#pragma unroll
        for (int it = 0; it < 8; ++it) {
            int r = it * 16 + lr;
            int s = sst ^ ((r >> 1) & 3);     // logical slot stored at phys sst
            gp[it] = gsrc + (rowbase + r) * (long)K + s * 8;
        }
    }

    f32x4 acc[4][4];
#pragma unroll
    for (int m = 0; m < 4; ++m)
#pragma unroll
        for (int n = 0; n < 4; ++n)
            acc[m][n] = (f32x4){0.f, 0.f, 0.f, 0.f};

    const int fr = lane & 15;
    const int sl = lane >> 4;                // logical k-slot of this lane

    for (int k0 = 0; k0 < kmax; k0 += 32) {
        __syncthreads();                      // all waves done reading prev tile
#if HAS_GLL
#pragma unroll
        for (int it = 0; it < 8; ++it)
            __builtin_amdgcn_global_load_lds(
                (const __attribute__((address_space(1))) unsigned int*)(gp[it] + k0),
                (__attribute__((address_space(3))) unsigned int*)&lds[wv][it * 512],
                16, 0, 0);
#else
        uint4 tmp[8];
#pragma unroll
        for (int it = 0; it < 8; ++it) tmp[it] = *(const uint4*)(gp[it] + k0);
#pragma unroll
        for (int it = 0; it < 8; ++it)
            *(uint4*)&lds[wv][it * 512 + (lane << 3)] = tmp[it];
#endif
        __syncthreads();                      // drains vmcnt -> tile ready

        bf16x8 fah[4], fal[4], fbh[4], fbl[4];
#pragma unroll
        for (int m = 0; m < 4; ++m) {
            int row = wr * 64 + m * 16 + fr;
            int po = row * 32 + ((sl ^ ((row >> 1) & 3)) << 3);
            fah[m] = *(const bf16x8*)&lds[0][po];
            fal[m] = *(const bf16x8*)&lds[1][po];
        }
#pragma unroll
        for (int n = 0; n < 4; ++n) {
            int row = wc * 64 + n * 16 + fr;
            int po = row * 32 + ((sl ^ ((row >> 1) & 3)) << 3);
            fbh[n] = *(const bf16x8*)&lds[2][po];
            fbl[n] = *(const bf16x8*)&lds[3][po];
        }
#pragma unroll
        for (int m = 0; m < 4; ++m)
#pragma unroll
            for (int n = 0; n < 4; ++n) {
                acc[m][n] = __builtin_amdgcn_mfma_f32_16x16x32_bf16(fah[m], fbh[n], acc[m][n], 0, 0, 0);
                acc[m][n] = __builtin_amdgcn_mfma_f32_16x16x32_bf16(fah[m], fbl[n], acc[m][n], 0, 0, 0);
                acc[m][n] = __builtin_amdgcn_mfma_f32_16x16x32_bf16(fal[m], fbh[n], acc[m][n], 0, 0, 0);
            }
    }

    // ---- epilogue math, in place on acc ----
    const long growbase = (long)bm * 128;
    const int gcolbase = bn * 128;
#pragma unroll
    for (int m = 0; m < 4; ++m) {
#pragma unroll
        for (int q = 0; q < 4; ++q) {
            const int rl = wr * 64 + m * 16 + ((lane >> 4) << 2) + q;
            const long grow = growbase + rl;
            const long rbase = cbase + grow * (long)N;
#pragma unroll
            for (int n = 0; n < 4; ++n) {
                const int cl = wc * 64 + n * 16 + (lane & 15);
                const int col = gcolbase + cl;
                float v = acc[m][n][q];
                if (bias) v += bias[col];
                if (ACT == 1) v = fmaxf(v, 0.f);
                if (ACT == 2) v = (v > 0.f) ? v + 1.f : expf(v);
                if (PE) {
                    int t = (int)(grow >> 4);          // token index (B=16)
                    int ih = col >> 1;
                    float dv = expf((float)ih * (-9.210340371976184f / 512.0f));
                    float ang = (float)t * dv;
                    v += (col & 1) ? cosf(ang) : sinf(ang);
                }
                if (CAUSAL && ((col >> 4) > (int)(grow >> 4))) v = 0.f;
                if (AOUT) {
                    v = (v + Cf[rbase + col]) / den[(long)cz * RC + grow] + Rf[rbase + col];
                } else {
                    if (accf) v += Cf[rbase + col];
                    if (Rf) v += Rf[rbase + col];
                }
                acc[m][n][q] = v;
            }
        }
    }

    // ---- LDS-staged coalesced writeback ----
    ushort* LS = (ushort*)&lds[0][0];
    if (Ch) {
        // hi plane
        __syncthreads();
#pragma unroll
        for (int m = 0; m < 4; ++m)
#pragma unroll
            for (int q = 0; q < 4; ++q) {
                const int rl = wr * 64 + m * 16 + ((lane >> 4) << 2) + q;
#pragma unroll
                for (int n = 0; n < 4; ++n) {
                    const int cl = wc * 64 + n * 16 + (lane & 15);
                    LS[sidx16(rl, cl)] = f2bf(acc[m][n][q]);
                }
            }
        __syncthreads();
        {
            const int r = tid >> 1, cb = (tid & 1) * 64;
            long gof = cbase + (growbase + r) * (long)N + gcolbase + cb;
#pragma unroll
            for (int i = 0; i < 8; ++i)
                *(uint4*)(Ch + gof + i * 8) = *(const uint4*)&LS[sidx16(r, cb + i * 8)];
        }
        // lo plane
        __syncthreads();
#pragma unroll
        for (int m = 0; m < 4; ++m)
#pragma unroll
            for (int q = 0; q < 4; ++q) {
                const int rl = wr * 64 + m * 16 + ((lane >> 4) << 2) + q;
#pragma unroll
                for (int n = 0; n < 4; ++n) {
                    const int cl = wc * 64 + n * 16 + (lane & 15);
                    float v = acc[m][n][q];
                    ushort hh = f2bf(v);
                    LS[sidx16(rl, cl)] = f2bf(v - bf2f(hh));
                }
            }
        __syncthreads();
        {
            const int r = tid >> 1, cb = (tid & 1) * 64;
            long gof = cbase + (growbase + r) * (long)N + gcolbase + cb;
#pragma unroll
            for (int i = 0; i < 8; ++i)
                *(uint4*)(Cl + gof + i * 8) = *(const uint4*)&LS[sidx16(r, cb + i * 8)];
        }
    }
    if (Cf && !AOUT) {
        float* LF = (float*)&lds[0][0];
        for (int half = 0; half < 2; ++half) {
            __syncthreads();
            if (wr == half) {
#pragma unroll
                for (int m = 0; m < 4; ++m)
#pragma unroll
                    for (int q = 0; q < 4; ++q) {
                        const int rl = (wr * 64 + m * 16 + ((lane >> 4) << 2) + q) - half * 64;
#pragma unroll
                        for (int n = 0; n < 4; ++n) {
                            const int cl = wc * 64 + n * 16 + (lane & 15);
                            LF[sidxf(rl, cl)] = acc[m][n][q];
                        }
                    }
            }
            __syncthreads();
            {
                const int r = tid >> 2, cb = (tid & 3) * 32;
                long gof = cbase + (growbase + half * 64 + r) * (long)N + gcolbase + cb;
#pragma unroll
                for (int i = 0; i < 8; ++i)
                    *(float4*)(Cf + gof + i * 4) = *(const float4*)&LF[sidxf(r, cb + i * 4)];
            }
        }
    }
}

// ---------------- fp32 -> hi/lo bf16 planes --------------------------------
__global__ __launch_bounds__(256) void split_kernel(
    const float* __restrict__ s, ushort* __restrict__ h, ushort* __restrict__ l, long n)
{
    for (long i = ((long)blockIdx.x * 256 + threadIdx.x) * 4; i < n;
         i += (long)gridDim.x * 1024) {
        float4 v = *(const float4*)(s + i);
        ushort4 hh, ll;
        split2(v.x, hh.x, ll.x); split2(v.y, hh.y, ll.y);
        split2(v.z, hh.z, ll.z); split2(v.w, hh.w, ll.w);
        *(ushort4*)(h + i) = hh;
        *(ushort4*)(l + i) = ll;
    }
}

// ---------------- per-chunk plane transpose [RC][DM] -> [DM][RC] -----------
__global__ __launch_bounds__(256) void transpose_plane(
    const ushort* __restrict__ src, ushort* __restrict__ dst)
{
    long c = blockIdx.z;
    src += c * (long)RC * DM;
    dst += c * (long)DM * RC;
    int r0 = blockIdx.y * 32, c0 = blockIdx.x * 32;
    __shared__ ushort t[32][36];
    int tr = threadIdx.x >> 3, tc = (threadIdx.x & 7) * 4;
    ushort4 v = *(const ushort4*)(src + (long)(r0 + tr) * DM + c0 + tc);
    t[tr][tc] = v.x; t[tr][tc + 1] = v.y; t[tr][tc + 2] = v.z; t[tr][tc + 3] = v.w;
    __syncthreads();
    ushort4 o;
    o.x = t[tc + 0][tr]; o.y = t[tc + 1][tr]; o.z = t[tc + 2][tr]; o.w = t[tc + 3][tr];
    *(ushort4*)(dst + (long)(c0 + tr) * RC + r0 + tc) = o;
}

// -------- exclusive prefix of Gt over chunks, emits bf16 planes ------------
__global__ __launch_bounds__(256) void gprefix_split(
    const float* __restrict__ G, ushort* __restrict__ Gh, ushort* __restrict__ Gl)
{
    long e = ((long)blockIdx.x * 256 + threadIdx.x) * 4;   // < DM*DM
    float4 run = {0.f, 0.f, 0.f, 0.f};
    for (int c = 0; c < NCH; ++c) {
        long off = (long)c * DM * DM + e;
        float4 t = *(const float4*)(G + off);
        ushort4 hh, ll;
        split2(run.x, hh.x, ll.x); split2(run.y, hh.y, ll.y);
        split2(run.z, hh.z, ll.z); split2(run.w, hh.w, ll.w);
        *(ushort4*)(Gh + off) = hh;
        *(ushort4*)(Gl + off) = ll;
        run.x += t.x; run.y += t.y; run.z += t.z; run.w += t.w;
    }
}

// ---------------- denominator side path (reads hi/lo planes) ---------------
__global__ __launch_bounds__(256) void zpart_kernel(
    const ushort* __restrict__ Kh, const ushort* __restrict__ Kl,
    float* __restrict__ Zp)
{
    int c = blockIdx.x, b = blockIdx.y;
    int d = threadIdx.x * 4;
    float4 acc = {0.f, 0.f, 0.f, 0.f};
    for (int t = 0; t < LC; ++t) {
        long row = (long)(c * LC + t) * NB + b;
        ushort4 h = *(const ushort4*)(Kh + row * DM + d);
        ushort4 l = *(const ushort4*)(Kl + row * DM + d);
        acc.x += rc1(h.x, l.x); acc.y += rc1(h.y, l.y);
        acc.z += rc1(h.z, l.z); acc.w += rc1(h.w, l.w);
    }
    *(float4*)(Zp + (long)(c * NB + b) * DM + d) = acc;
}

__global__ __launch_bounds__(256) void zprefix_kernel(float* __restrict__ Zp)
{
    int idx = blockIdx.x * 256 + threadIdx.x;   // < NB*256
    int b = idx >> 8;
    int d = (idx & 255) * 4;
    float4 run = {0.f, 0.f, 0.f, 0.f};
    for (int c = 0; c < NCH; ++c) {
        float4* p = (float4*)(Zp + (long)(c * NB + b) * DM + d);
        float4 t = *p; *p = run;
        run.x += t.x; run.y += t.y; run.z += t.z; run.w += t.w;
    }
}

__global__ __launch_bounds__(256) void denom_kernel(
    const ushort* __restrict__ Qh, const ushort* __restrict__ Ql,
    const ushort* __restrict__ Kh, const ushort* __restrict__ Kl,
    const float* __restrict__ Zp, float* __restrict__ den)
{
    int wave = threadIdx.x >> 6, lane = threadIdx.x & 63;
    int cb = blockIdx.x * 4 + wave;     // 0..511
    int c = cb >> 4, b = cb & 15;
    float z[16];
    {
        const float* zp = Zp + (long)(c * NB + b) * DM + lane * 16;
#pragma unroll
        for (int i = 0; i < 16; ++i) z[i] = zp[i];
    }
    for (int t = 0; t < LC; ++t) {
        long ro = ((long)(c * LC + t) * NB + b) * DM + lane * 16;
        float p = 0.f;
#pragma unroll
        for (int g = 0; g < 4; ++g) {
            ushort4 kh = *(const ushort4*)(Kh + ro + g * 4);
            ushort4 kl = *(const ushort4*)(Kl + ro + g * 4);
            ushort4 qh = *(const ushort4*)(Qh + ro + g * 4);
            ushort4 ql = *(const ushort4*)(Ql + ro + g * 4);
            z[g * 4 + 0] += rc1(kh.x, kl.x);
            z[g * 4 + 1] += rc1(kh.y, kl.y);
            z[g * 4 + 2] += rc1(kh.z, kl.z);
            z[g * 4 + 3] += rc1(kh.w, kl.w);
            p += rc1(qh.x, ql.x) * z[g * 4 + 0] + rc1(qh.y, ql.y) * z[g * 4 + 1]
               + rc1(qh.z, ql.z) * z[g * 4 + 2] + rc1(qh.w, ql.w) * z[g * 4 + 3];
        }
#pragma unroll
        for (int off = 32; off > 0; off >>= 1) p += __shfl_down(p, off);
        if (lane == 0) den[(long)(c * LC + t) * NB + b] = p;
    }
}

// ---------------- row softmax over 512 cols (in place) ---------------------
__global__ __launch_bounds__(256) void softmax_kernel(float* __restrict__ io)
{
    int wave = threadIdx.x >> 6, lane = threadIdx.x & 63;
    long row = (long)blockIdx.x * 4 + wave;
    float* p = io + row * DIO + lane * 8;
    float4 a = *(float4*)p, b = *(float4*)(p + 4);
    float m = fmaxf(fmaxf(fmaxf(a.x, a.y), fmaxf(a.z, a.w)),
                    fmaxf(fmaxf(b.x, b.y), fmaxf(b.z, b.w)));
#pragma unroll
    for (int off = 32; off > 0; off >>= 1) m = fmaxf(m, __shfl_xor(m, off));
    a.x = expf(a.x - m); a.y = expf(a.y - m); a.z = expf(a.z - m); a.w = expf(a.w - m);
    b.x = expf(b.x - m); b.y = expf(b.y - m); b.z = expf(b.z - m); b.w = expf(b.w - m);
    float s = a.x + a.y + a.z + a.w + b.x + b.y + b.z + b.w;
#pragma unroll
    for (int off = 32; off > 0; off >>= 1) s += __shfl_xor(s, off);
    float inv = 1.0f / s;
    a.x *= inv; a.y *= inv; a.z *= inv; a.w *= inv;
    b.x *= inv; b.y *= inv; b.z *= inv; b.w *= inv;
    *(float4*)p = a; *(float4*)(p + 4) = b;
}

// ---------------------------------------------------------------------------
#define F32BUF   134217728L                 // ROWS*DM*4 bytes
#define PLANE    67108864L                  // ROWS*DM*2 bytes
#define XPLANE   33554432L                  // ROWS*DIO*2 bytes
#define WSMALL   1048576L                   // DM*DIO*2 bytes
#define WBIG     6291456L                   // 3*DM*DM*2 bytes
#define NEED     (2L*F32BUF + 16L*PLANE + 2L*XPLANE + 4L*WSMALL + 10L*WBIG + 131072L + 2097152L)

__device__ __attribute__((aligned(1024))) unsigned char g_ws[NEED];

extern "C" void kernel_launch(void* const* d_in, const int* in_sizes, int n_in,
                              void* d_out, int out_size, void* d_ws, size_t ws_size,
                              hipStream_t stream)
{
    const float* x    = (const float*)d_in[0];
    const float* in_W = (const float*)d_in[1];
    const float* in_b = (const float*)d_in[2];
    const float* Wq   = (const float*)d_in[3];
    const float* Wk   = (const float*)d_in[4];
    const float* Wv   = (const float*)d_in[5];
    const float* h1W  = (const float*)d_in[6];
    const float* h1b  = (const float*)d_in[7];
    const float* h2W  = (const float*)d_in[8];
    const float* h2b  = (const float*)d_in[9];
    const float* outW = (const float*)d_in[10];
    const float* outb = (const float*)d_in[11];
    float* out = (float*)d_out;

    unsigned char* base;
    if (ws_size >= (size_t)NEED) {
        base = (unsigned char*)d_ws;
    } else {
        static unsigned char* g_fb = nullptr;   // resolved on first (uncaptured) call
        if (!g_fb) hipGetSymbolAddress((void**)&g_fb, HIP_SYMBOL(g_ws));
        base = g_fb;
    }

    unsigned char* p = base;
    float* hF  = (float*)p;  p += F32BUF;
    float* GtF = (float*)p;  p += F32BUF;     // chunk states / "numer"
    ushort* hh  = (ushort*)p; p += PLANE;  ushort* hl  = (ushort*)p; p += PLANE;
    ushort* Qh  = (ushort*)p; p += PLANE;  ushort* Ql  = (ushort*)p; p += PLANE;  // also g1 planes
    ushort* Kh  = (ushort*)p; p += PLANE;  ushort* Kl  = (ushort*)p; p += PLANE;
    ushort* Vh  = (ushort*)p; p += PLANE;  ushort* Vl  = (ushort*)p; p += PLANE;
    ushort* Kth = (ushort*)p; p += PLANE;  ushort* Ktl = (ushort*)p; p += PLANE;  // also xattn planes
    ushort* Vth = (ushort*)p; p += PLANE;  ushort* Vtl = (ushort*)p; p += PLANE;
    ushort* Gth = (ushort*)p; p += PLANE;  ushort* Gtl = (ushort*)p; p += PLANE;
    ushort* Ph  = (ushort*)p; p += PLANE;  ushort* Pl  = (ushort*)p; p += PLANE;
    ushort* xh  = (ushort*)p; p += XPLANE; ushort* xl  = (ushort*)p; p += XPLANE;
    ushort* iWh = (ushort*)p; p += WSMALL; ushort* iWl = (ushort*)p; p += WSMALL;
    ushort* oWh = (ushort*)p; p += WSMALL; ushort* oWl = (ushort*)p; p += WSMALL;
    ushort* Wqh = (ushort*)p; p += WBIG;   ushort* Wql = (ushort*)p; p += WBIG;
    ushort* Wkh = (ushort*)p; p += WBIG;   ushort* Wkl = (ushort*)p; p += WBIG;
    ushort* Wvh = (ushort*)p; p += WBIG;   ushort* Wvl = (ushort*)p; p += WBIG;
    ushort* W1h = (ushort*)p; p += WBIG;   ushort* W1l = (ushort*)p; p += WBIG;
    ushort* W2h = (ushort*)p; p += WBIG;   ushort* W2l = (ushort*)p; p += WBIG;
    float* den = (float*)p;  p += 131072L;
    float* Zp  = (float*)p;  p += 2097152L;

    const long CS = (long)RC * DM;              // chunk stride (=DM*DM=RC*RC)
    dim3 gFull(DM / 128, ROWS / 128);           // (8,256)  nwg=2048 %8==0
    dim3 gChunk(DM / 128, RC / 128, NCH);       // (8,8,32) nwg/slice=64 %8==0
    dim3 gOut(DIO / 128, ROWS / 128);           // (4,256)  nwg=1024 %8==0
    dim3 gTr(DM / 32, RC / 32, NCH);

    // ---- splits of inputs/weights into bf16 planes ----
    split_kernel<<<2048, 256, 0, stream>>>(x, xh, xl, (long)ROWS * DIO);
    split_kernel<<<2048, 256, 0, stream>>>(in_W, iWh, iWl, (long)DM * DIO);
    split_kernel<<<2048, 256, 0, stream>>>(outW, oWh, oWl, (long)DIO * DM);
    split_kernel<<<2048, 256, 0, stream>>>(Wq, Wqh, Wql, 3L * DM * DM);
    split_kernel<<<2048, 256, 0, stream>>>(Wk, Wkh, Wkl, 3L * DM * DM);
    split_kernel<<<2048, 256, 0, stream>>>(Wv, Wvh, Wvl, 3L * DM * DM);
    split_kernel<<<2048, 256, 0, stream>>>(h1W, W1h, W1l, 3L * DM * DM);
    split_kernel<<<2048, 256, 0, stream>>>(h2W, W2h, W2l, 3L * DM * DM);

    // ---- h = relu(x @ inW^T + b) + PE ----
    mgemm<1, true, false, false, false><<<gFull, 256, 0, stream>>>(
        xh, xl, iWh, iWl, in_b, hF, hh, hl, nullptr, nullptr, 0,
        ROWS, DM, DIO, 0, 0, 0);

    for (int l = 0; l < NLAYER; ++l) {
        long wo = (long)l * DM * DM;

        mgemm<2, false, false, false, false><<<gFull, 256, 0, stream>>>(
            hh, hl, Wqh + wo, Wql + wo, nullptr, nullptr, Qh, Ql, nullptr, nullptr, 0,
            ROWS, DM, DM, 0, 0, 0);
        mgemm<2, false, false, false, false><<<gFull, 256, 0, stream>>>(
            hh, hl, Wkh + wo, Wkl + wo, nullptr, nullptr, Kh, Kl, nullptr, nullptr, 0,
            ROWS, DM, DM, 0, 0, 0);
        mgemm<0, false, false, false, false><<<gFull, 256, 0, stream>>>(
            hh, hl, Wvh + wo, Wvl + wo, nullptr, nullptr, Vh, Vl, nullptr, nullptr, 0,
            ROWS, DM, DM, 0, 0, 0);

        transpose_plane<<<gTr, 256, 0, stream>>>(Kh, Kth);
        transpose_plane<<<gTr, 256, 0, stream>>>(Kl, Ktl);
        transpose_plane<<<gTr, 256, 0, stream>>>(Vh, Vth);
        transpose_plane<<<gTr, 256, 0, stream>>>(Vl, Vtl);

        // denominator path (needs Q,K planes only)
        zpart_kernel<<<dim3(NCH, NB), 256, 0, stream>>>(Kh, Kl, Zp);
        zprefix_kernel<<<NB, 256, 0, stream>>>(Zp);
        denom_kernel<<<128, 256, 0, stream>>>(Qh, Ql, Kh, Kl, Zp, den);

        // Gt[c][i,n] = sum_r V[r,i] K[r,n]  (A=Vt, B=Kt)
        mgemm<0, false, false, false, false><<<gChunk, 256, 0, stream>>>(
            Vth, Vtl, Kth, Ktl, nullptr, GtF, nullptr, nullptr, nullptr, nullptr, 0,
            DM, DM, RC, CS, CS, CS);
        gprefix_split<<<1024, 256, 0, stream>>>(GtF, Gth, Gtl);

        // numer = Q_c @ S_prev  (B = Gt planes); overwrites GtF buffer
        mgemm<0, false, false, false, false><<<gChunk, 256, 0, stream>>>(
            Qh, Ql, Gth, Gtl, nullptr, GtF, nullptr, nullptr, nullptr, nullptr, 0,
            RC, DM, DM, CS, CS, CS);
        // P = Q_c K_c^T (causal)
        mgemm<0, false, true, false, false><<<gChunk, 256, 0, stream>>>(
            Qh, Ql, Kh, Kl, nullptr, nullptr, Ph, Pl, nullptr, nullptr, 0,
            RC, RC, DM, CS, CS, CS);
        // xattn = (P @ V_c + numer)/den + h -> planes (reuse Kt buffers)
        mgemm<0, false, false, true, true><<<gChunk, 256, 0, stream>>>(
            Ph, Pl, Vth, Vtl, nullptr, GtF, Kth, Ktl, hF, den, 0,
            RC, DM, RC, CS, CS, CS);

        // FFN1: g1 = relu(xattn @ h1W^T + b1) -> planes (reuse Q plane bufs)
        mgemm<1, false, false, false, false><<<gFull, 256, 0, stream>>>(
            Kth, Ktl, W1h + wo, W1l + wo, h1b + (long)l * DM,
            nullptr, Qh, Ql, nullptr, nullptr, 0, ROWS, DM, DM, 0, 0, 0);
        // FFN2: h = h + g1 @ h2W^T + b2  (fp32 + planes)
        mgemm<0, false, false, false, false><<<gFull, 256, 0, stream>>>(
            Qh, Ql, W2h + wo, W2l + wo, h2b + (long)l * DM,
            hF, hh, hl, hF, nullptr, 0, ROWS, DM, DM, 0, 0, 0);
    }

    // logits -> d_out, softmax in place
    mgemm<0, false, false, false, false><<<gOut, 256, 0, stream>>>(
        hh, hl, oWh, oWl, outb, out, nullptr, nullptr, nullptr, nullptr, 0,
        ROWS, DIO, DM, 0, 0, 0);
    softmax_kernel<<<ROWS / 4, 256, 0, stream>>>(out);
}

// Round 9
// 8678.572 us; speedup vs baseline: 1.7439x; 1.7439x over previous
//
#include <hip/hip_runtime.h>
#include <math.h>

// ---------------------------------------------------------------------------
// LinTransformer, round 9: back to verified split-bf16 (bf16x3) numerics
// (round-3 kernel), + spill fix:
//   - __launch_bounds__(256, 2): VGPR cap 256 (round 3 compiled at 88 VGPR
//     with a >=128-reg live set -> acc/fragment SPILL; scratch writes were
//     the 18x WRITE_SIZE amplification)
//   - register-lean inner loop: B-fragments loaded once per k-step,
//     A-fragments streamed per-m
//   - AOUT fusion kept (verified in round 5): xattn=(PV+numer)/den+h
// Every GEMM is NT (C = A * B^T) on 16x16x32 bf16 MFMA with fp32 accum:
//   A = Ah + Al, B = Bh + Bl;  C ~= Ah*Bh + Ah*Bl + Al*Bh.
// ---------------------------------------------------------------------------

#define SEQ    2048
#define NB     16
#define DIO    512
#define DM     1024
#define NLAYER 3
#define ROWS   (SEQ * NB)      // 32768
#define LC     64
#define NCH    (SEQ / LC)      // 32
#define RC     (LC * NB)       // 1024

typedef __attribute__((ext_vector_type(8))) short bf16x8;
typedef __attribute__((ext_vector_type(4))) float f32x4;

#if defined(__has_builtin)
#if __has_builtin(__builtin_amdgcn_global_load_lds)
#define HAS_GLL 1
#endif
#endif

__device__ __forceinline__ ushort f2bf(float f) {
    unsigned u = __float_as_uint(f);
    return (ushort)((u + 0x7fffu + ((u >> 16) & 1u)) >> 16);
}
__device__ __forceinline__ float bf2f(ushort h) {
    return __uint_as_float((unsigned)h << 16);
}
__device__ __forceinline__ void split2(float f, ushort& h, ushort& l) {
    h = f2bf(f);
    l = f2bf(f - bf2f(h));
}
__device__ __forceinline__ float rc1(ushort h, ushort l) {
    return bf2f(h) + bf2f(l);
}

// ---------------------------------------------------------------------------
// mgemm: C[m,n] = epilogue( sum_k A[m,k]*B[n,k] ), 128x128 tile, 4 waves,
// wave quadrant 64x64 = 4x4 fragments of 16x16, BK=32.
// LDS plane tile [128][32] ushort; 16B slot XOR-swizzled (phys = slot ^
// ((row>>1)&3)); global source pre-inverse-swizzled (both-sides rule).
// AOUT: v = (acc + Cf)/den + Rf (fused attn output; Cf read-only).
// ---------------------------------------------------------------------------
template <int ACT, bool PE, bool CAUSAL, bool KLIM, bool AOUT>
__global__ __launch_bounds__(256, 2) void mgemm(
    const ushort* __restrict__ Ah, const ushort* __restrict__ Al,
    const ushort* __restrict__ Bh, const ushort* __restrict__ Bl,
    const float* __restrict__ bias,
    float* __restrict__ Cf, ushort* __restrict__ Ch, ushort* __restrict__ Cl,
    const float* __restrict__ Rf, const float* __restrict__ den, int accf,
    int M, int N, int K, long sA, long sB, long sC)
{
    const int cz = blockIdx.z;
    Ah += (long)cz * sA; Al += (long)cz * sA;
    Bh += (long)cz * sB; Bl += (long)cz * sB;
    const long cbase = (long)cz * sC;

    // XCD-chunked bijective swizzle (all grids have nwg % 8 == 0)
    const int nx = gridDim.x;
    const int lin = blockIdx.y * nx + blockIdx.x;
    const int chunkpx = (nx * gridDim.y) >> 3;
    const int nl = (lin & 7) * chunkpx + (lin >> 3);
    const int bm = nl / nx, bn = nl % nx;

    if (CAUSAL && bn > bm) return;          // strictly-upper tiles: never read

    const int tid = threadIdx.x;
    const int lane = tid & 63;
    const int wv = tid >> 6;                 // wave 0..3
    const int wr = wv >> 1, wc = wv & 1;     // 2x2 wave grid

    __shared__ __align__(16) ushort lds[4][4096];   // Ah,Al,Bh,Bl planes, 32 KB

    const ushort* gsrc = (wv == 0) ? Ah : (wv == 1) ? Al : (wv == 2) ? Bh : Bl;
    const long rowbase = (long)((wv < 2 ? bm : bn) * 128);

    const int kmax = KLIM ? (((bm + 1) * 128 < K) ? (bm + 1) * 128 : K) : K;

    // per-lane pre-inverse-swizzled global source pointers (8 issues/plane)
    const ushort* gp[8];
    {
        const int lr = lane >> 2, sst = lane & 3;
#pragma unroll
        for (int it = 0; it < 8; ++it) {
            int r = it * 16 + lr;
            int s = sst ^ ((r >> 1) & 3);     // logical slot stored at phys sst
            gp[it] = gsrc + (rowbase + r) * (long)K + s * 8;
        }
    }

    f32x4 acc[4][4];
#pragma unroll
    for (int m = 0; m < 4; ++m)
#pragma unroll
        for (int n = 0; n < 4; ++n)
            acc[m][n] = (f32x4){0.f, 0.f, 0.f, 0.f};

    const int fr = lane & 15;
    const int sl = lane >> 4;                // logical k-slot of this lane

    for (int k0 = 0; k0 < kmax; k0 += 32) {
        __syncthreads();                      // all waves done reading prev tile
#if HAS_GLL
#pragma unroll
        for (int it = 0; it < 8; ++it)
            __builtin_amdgcn_global_load_lds(
                (const __attribute__((address_space(1))) unsigned int*)(gp[it] + k0),
                (__attribute__((address_space(3))) unsigned int*)&lds[wv][it * 512],
                16, 0, 0);
#else
        uint4 tmp[8];
#pragma unroll
        for (int it = 0; it < 8; ++it) tmp[it] = *(const uint4*)(gp[it] + k0);
#pragma unroll
        for (int it = 0; it < 8; ++it)
            *(uint4*)&lds[wv][it * 512 + (lane << 3)] = tmp[it];
#endif
        __syncthreads();                      // drains vmcnt -> tile ready

        // B fragments once per k-step (32 VGPRs live across the m-loop)
        bf16x8 fbh[4], fbl[4];
#pragma unroll
        for (int n = 0; n < 4; ++n) {
            int row = wc * 64 + n * 16 + fr;
            int po = row * 32 + ((sl ^ ((row >> 1) & 3)) << 3);
            fbh[n] = *(const bf16x8*)&lds[2][po];
            fbl[n] = *(const bf16x8*)&lds[3][po];
        }
        // stream A fragments per-m (8 VGPRs at a time)
#pragma unroll
        for (int m = 0; m < 4; ++m) {
            int row = wr * 64 + m * 16 + fr;
            int po = row * 32 + ((sl ^ ((row >> 1) & 3)) << 3);
            bf16x8 ah = *(const bf16x8*)&lds[0][po];
            bf16x8 al = *(const bf16x8*)&lds[1][po];
#pragma unroll
            for (int n = 0; n < 4; ++n) {
                acc[m][n] = __builtin_amdgcn_mfma_f32_16x16x32_bf16(ah, fbh[n], acc[m][n], 0, 0, 0);
                acc[m][n] = __builtin_amdgcn_mfma_f32_16x16x32_bf16(ah, fbl[n], acc[m][n], 0, 0, 0);
                acc[m][n] = __builtin_amdgcn_mfma_f32_16x16x32_bf16(al, fbh[n], acc[m][n], 0, 0, 0);
            }
        }
    }

    // epilogue (direct stores): C row = (lane>>4)*4 + q, col = lane&15
    const long crow0 = (long)bm * 128 + wr * 64;
    const int ccol0 = bn * 128 + wc * 64;
#pragma unroll
    for (int m = 0; m < 4; ++m) {
#pragma unroll
        for (int q = 0; q < 4; ++q) {
            long row = crow0 + m * 16 + ((lane >> 4) << 2) + q;
            long rbase = cbase + row * (long)N;
#pragma unroll
            for (int n = 0; n < 4; ++n) {
                int col = ccol0 + n * 16 + (lane & 15);
                float v = acc[m][n][q];
                if (bias) v += bias[col];
                if (ACT == 1) v = fmaxf(v, 0.f);
                if (ACT == 2) v = (v > 0.f) ? v + 1.f : expf(v);
                if (PE) {
                    int t = (int)(row >> 4);          // token index (B=16)
                    int ih = col >> 1;
                    float dv = expf((float)ih * (-9.210340371976184f / 512.0f));
                    float ang = (float)t * dv;
                    v += (col & 1) ? cosf(ang) : sinf(ang);
                }
                if (CAUSAL && ((col >> 4) > (int)(row >> 4))) v = 0.f;
                if (AOUT) {
                    v = (v + Cf[rbase + col]) / den[(long)cz * RC + row] + Rf[rbase + col];
                } else {
                    if (accf) v += Cf[rbase + col];
                    if (Rf) v += Rf[rbase + col];
                }
                if (Cf && !AOUT) Cf[rbase + col] = v;
                if (Ch) {
                    ushort hh, ll;
                    split2(v, hh, ll);
                    Ch[rbase + col] = hh;
                    Cl[rbase + col] = ll;
                }
            }
        }
    }
}

// ---------------- fp32 -> hi/lo bf16 planes --------------------------------
__global__ __launch_bounds__(256) void split_kernel(
    const float* __restrict__ s, ushort* __restrict__ h, ushort* __restrict__ l, long n)
{
    for (long i = ((long)blockIdx.x * 256 + threadIdx.x) * 4; i < n;
         i += (long)gridDim.x * 1024) {
        float4 v = *(const float4*)(s + i);
        ushort4 hh, ll;
        split2(v.x, hh.x, ll.x); split2(v.y, hh.y, ll.y);
        split2(v.z, hh.z, ll.z); split2(v.w, hh.w, ll.w);
        *(ushort4*)(h + i) = hh;
        *(ushort4*)(l + i) = ll;
    }
}

// ---------------- per-chunk plane transpose [RC][DM] -> [DM][RC] -----------
__global__ __launch_bounds__(256) void transpose_plane(
    const ushort* __restrict__ src, ushort* __restrict__ dst)
{
    long c = blockIdx.z;
    src += c * (long)RC * DM;
    dst += c * (long)DM * RC;
    int r0 = blockIdx.y * 32, c0 = blockIdx.x * 32;
    __shared__ ushort t[32][36];
    int tr = threadIdx.x >> 3, tc = (threadIdx.x & 7) * 4;
    ushort4 v = *(const ushort4*)(src + (long)(r0 + tr) * DM + c0 + tc);
    t[tr][tc] = v.x; t[tr][tc + 1] = v.y; t[tr][tc + 2] = v.z; t[tr][tc + 3] = v.w;
    __syncthreads();
    ushort4 o;
    o.x = t[tc + 0][tr]; o.y = t[tc + 1][tr]; o.z = t[tc + 2][tr]; o.w = t[tc + 3][tr];
    *(ushort4*)(dst + (long)(c0 + tr) * RC + r0 + tc) = o;
}

// -------- exclusive prefix of Gt over chunks, emits bf16 planes ------------
__global__ __launch_bounds__(256) void gprefix_split(
    const float* __restrict__ G, ushort* __restrict__ Gh, ushort* __restrict__ Gl)
{
    long e = ((long)blockIdx.x * 256 + threadIdx.x) * 4;   // < DM*DM
    float4 run = {0.f, 0.f, 0.f, 0.f};
    for (int c = 0; c < NCH; ++c) {
        long off = (long)c * DM * DM + e;
        float4 t = *(const float4*)(G + off);
        ushort4 hh, ll;
        split2(run.x, hh.x, ll.x); split2(run.y, hh.y, ll.y);
        split2(run.z, hh.z, ll.z); split2(run.w, hh.w, ll.w);
        *(ushort4*)(Gh + off) = hh;
        *(ushort4*)(Gl + off) = ll;
        run.x += t.x; run.y += t.y; run.z += t.z; run.w += t.w;
    }
}

// ---------------- denominator side path (reads hi/lo planes) ---------------
__global__ __launch_bounds__(256) void zpart_kernel(
    const ushort* __restrict__ Kh, const ushort* __restrict__ Kl,
    float* __restrict__ Zp)
{
    int c = blockIdx.x, b = blockIdx.y;
    int d = threadIdx.x * 4;
    float4 acc = {0.f, 0.f, 0.f, 0.f};
    for (int t = 0; t < LC; ++t) {
        long row = (long)(c * LC + t) * NB + b;
        ushort4 h = *(const ushort4*)(Kh + row * DM + d);
        ushort4 l = *(const ushort4*)(Kl + row * DM + d);
        acc.x += rc1(h.x, l.x); acc.y += rc1(h.y, l.y);
        acc.z += rc1(h.z, l.z); acc.w += rc1(h.w, l.w);
    }
    *(float4*)(Zp + (long)(c * NB + b) * DM + d) = acc;
}

__global__ __launch_bounds__(256) void zprefix_kernel(float* __restrict__ Zp)
{
    int idx = blockIdx.x * 256 + threadIdx.x;   // < NB*256
    int b = idx >> 8;
    int d = (idx & 255) * 4;
    float4 run = {0.f, 0.f, 0.f, 0.f};
    for (int c = 0; c < NCH; ++c) {
        float4* p = (float4*)(Zp + (long)(c * NB + b) * DM + d);
        float4 t = *p; *p = run;
        run.x += t.x; run.y += t.y; run.z += t.z; run.w += t.w;
    }
}

__global__ __launch_bounds__(256) void denom_kernel(
    const ushort* __restrict__ Qh, const ushort* __restrict__ Ql,
    const ushort* __restrict__ Kh, const ushort* __restrict__ Kl,
    const float* __restrict__ Zp, float* __restrict__ den)
{
    int wave = threadIdx.x >> 6, lane = threadIdx.x & 63;
    int cb = blockIdx.x * 4 + wave;     // 0..511
    int c = cb >> 4, b = cb & 15;
    float z[16];
    {
        const float* zp = Zp + (long)(c * NB + b) * DM + lane * 16;
#pragma unroll
        for (int i = 0; i < 16; ++i) z[i] = zp[i];
    }
    for (int t = 0; t < LC; ++t) {
        long ro = ((long)(c * LC + t) * NB + b) * DM + lane * 16;
        float p = 0.f;
#pragma unroll
        for (int g = 0; g < 4; ++g) {
            ushort4 kh = *(const ushort4*)(Kh + ro + g * 4);
            ushort4 kl = *(const ushort4*)(Kl + ro + g * 4);
            ushort4 qh = *(const ushort4*)(Qh + ro + g * 4);
            ushort4 ql = *(const ushort4*)(Ql + ro + g * 4);
            z[g * 4 + 0] += rc1(kh.x, kl.x);
            z[g * 4 + 1] += rc1(kh.y, kl.y);
            z[g * 4 + 2] += rc1(kh.z, kl.z);
            z[g * 4 + 3] += rc1(kh.w, kl.w);
            p += rc1(qh.x, ql.x) * z[g * 4 + 0] + rc1(qh.y, ql.y) * z[g * 4 + 1]
               + rc1(qh.z, ql.z) * z[g * 4 + 2] + rc1(qh.w, ql.w) * z[g * 4 + 3];
        }
#pragma unroll
        for (int off = 32; off > 0; off >>= 1) p += __shfl_down(p, off);
        if (lane == 0) den[(long)(c * LC + t) * NB + b] = p;
    }
}

// ---------------- row softmax over 512 cols (in place) ---------------------
__global__ __launch_bounds__(256) void softmax_kernel(float* __restrict__ io)
{
    int wave = threadIdx.x >> 6, lane = threadIdx.x & 63;
    long row = (long)blockIdx.x * 4 + wave;
    float* p = io + row * DIO + lane * 8;
    float4 a = *(float4*)p, b = *(float4*)(p + 4);
    float m = fmaxf(fmaxf(fmaxf(a.x, a.y), fmaxf(a.z, a.w)),
                    fmaxf(fmaxf(b.x, b.y), fmaxf(b.z, b.w)));
#pragma unroll
    for (int off = 32; off > 0; off >>= 1) m = fmaxf(m, __shfl_xor(m, off));
    a.x = expf(a.x - m); a.y = expf(a.y - m); a.z = expf(a.z - m); a.w = expf(a.w - m);
    b.x = expf(b.x - m); b.y = expf(b.y - m); b.z = expf(b.z - m); b.w = expf(b.w - m);
    float s = a.x + a.y + a.z + a.w + b.x + b.y + b.z + b.w;
#pragma unroll
    for (int off = 32; off > 0; off >>= 1) s += __shfl_xor(s, off);
    float inv = 1.0f / s;
    a.x *= inv; a.y *= inv; a.z *= inv; a.w *= inv;
    b.x *= inv; b.y *= inv; b.z *= inv; b.w *= inv;
    *(float4*)p = a; *(float4*)(p + 4) = b;
}

// ---------------------------------------------------------------------------
#define F32BUF   134217728L                 // ROWS*DM*4 bytes
#define PLANE    67108864L                  // ROWS*DM*2 bytes
#define XPLANE   33554432L                  // ROWS*DIO*2 bytes
#define WSMALL   1048576L                   // DM*DIO*2 bytes
#define WBIG     6291456L                   // 3*DM*DM*2 bytes
#define NEED     (2L*F32BUF + 16L*PLANE + 2L*XPLANE + 4L*WSMALL + 10L*WBIG + 131072L + 2097152L)

__device__ __attribute__((aligned(1024))) unsigned char g_ws[NEED];

extern "C" void kernel_launch(void* const* d_in, const int* in_sizes, int n_in,
                              void* d_out, int out_size, void* d_ws, size_t ws_size,
                              hipStream_t stream)
{
    const float* x    = (const float*)d_in[0];
    const float* in_W = (const float*)d_in[1];
    const float* in_b = (const float*)d_in[2];
    const float* Wq   = (const float*)d_in[3];
    const float* Wk   = (const float*)d_in[4];
    const float* Wv   = (const float*)d_in[5];
    const float* h1W  = (const float*)d_in[6];
    const float* h1b  = (const float*)d_in[7];
    const float* h2W  = (const float*)d_in[8];
    const float* h2b  = (const float*)d_in[9];
    const float* outW = (const float*)d_in[10];
    const float* outb = (const float*)d_in[11];
    float* out = (float*)d_out;

    unsigned char* base;
    if (ws_size >= (size_t)NEED) {
        base = (unsigned char*)d_ws;
    } else {
        static unsigned char* g_fb = nullptr;   // resolved on first (uncaptured) call
        if (!g_fb) hipGetSymbolAddress((void**)&g_fb, HIP_SYMBOL(g_ws));
        base = g_fb;
    }

    unsigned char* p = base;
    float* hF  = (float*)p;  p += F32BUF;
    float* GtF = (float*)p;  p += F32BUF;     // chunk states / "numer"
    ushort* hh  = (ushort*)p; p += PLANE;  ushort* hl  = (ushort*)p; p += PLANE;
    ushort* Qh  = (ushort*)p; p += PLANE;  ushort* Ql  = (ushort*)p; p += PLANE;  // also g1 planes
    ushort* Kh  = (ushort*)p; p += PLANE;  ushort* Kl  = (ushort*)p; p += PLANE;
    ushort* Vh  = (ushort*)p; p += PLANE;  ushort* Vl  = (ushort*)p; p += PLANE;
    ushort* Kth = (ushort*)p; p += PLANE;  ushort* Ktl = (ushort*)p; p += PLANE;  // also xattn planes
    ushort* Vth = (ushort*)p; p += PLANE;  ushort* Vtl = (ushort*)p; p += PLANE;
    ushort* Gth = (ushort*)p; p += PLANE;  ushort* Gtl = (ushort*)p; p += PLANE;
    ushort* Ph  = (ushort*)p; p += PLANE;  ushort* Pl  = (ushort*)p; p += PLANE;
    ushort* xh  = (ushort*)p; p += XPLANE; ushort* xl  = (ushort*)p; p += XPLANE;
    ushort* iWh = (ushort*)p; p += WSMALL; ushort* iWl = (ushort*)p; p += WSMALL;
    ushort* oWh = (ushort*)p; p += WSMALL; ushort* oWl = (ushort*)p; p += WSMALL;
    ushort* Wqh = (ushort*)p; p += WBIG;   ushort* Wql = (ushort*)p; p += WBIG;
    ushort* Wkh = (ushort*)p; p += WBIG;   ushort* Wkl = (ushort*)p; p += WBIG;
    ushort* Wvh = (ushort*)p; p += WBIG;   ushort* Wvl = (ushort*)p; p += WBIG;
    ushort* W1h = (ushort*)p; p += WBIG;   ushort* W1l = (ushort*)p; p += WBIG;
    ushort* W2h = (ushort*)p; p += WBIG;   ushort* W2l = (ushort*)p; p += WBIG;
    float* den = (float*)p;  p += 131072L;
    float* Zp  = (float*)p;  p += 2097152L;

    const long CS = (long)RC * DM;              // chunk stride (=DM*DM=RC*RC)
    dim3 gFull(DM / 128, ROWS / 128);           // (8,256)  nwg=2048 %8==0
    dim3 gChunk(DM / 128, RC / 128, NCH);       // (8,8,32) per-z 64 %8==0
    dim3 gOut(DIO / 128, ROWS / 128);           // (4,256)  nwg=1024 %8==0
    dim3 gTr(DM / 32, RC / 32, NCH);

    // ---- splits of inputs/weights into bf16 planes ----
    split_kernel<<<2048, 256, 0, stream>>>(x, xh, xl, (long)ROWS * DIO);
    split_kernel<<<2048, 256, 0, stream>>>(in_W, iWh, iWl, (long)DM * DIO);
    split_kernel<<<2048, 256, 0, stream>>>(outW, oWh, oWl, (long)DIO * DM);
    split_kernel<<<2048, 256, 0, stream>>>(Wq, Wqh, Wql, 3L * DM * DM);
    split_kernel<<<2048, 256, 0, stream>>>(Wk, Wkh, Wkl, 3L * DM * DM);
    split_kernel<<<2048, 256, 0, stream>>>(Wv, Wvh, Wvl, 3L * DM * DM);
    split_kernel<<<2048, 256, 0, stream>>>(h1W, W1h, W1l, 3L * DM * DM);
    split_kernel<<<2048, 256, 0, stream>>>(h2W, W2h, W2l, 3L * DM * DM);

    // ---- h = relu(x @ inW^T + b) + PE ----
    mgemm<1, true, false, false, false><<<gFull, 256, 0, stream>>>(
        xh, xl, iWh, iWl, in_b, hF, hh, hl, nullptr, nullptr, 0,
        ROWS, DM, DIO, 0, 0, 0);

    for (int l = 0; l < NLAYER; ++l) {
        long wo = (long)l * DM * DM;

        mgemm<2, false, false, false, false><<<gFull, 256, 0, stream>>>(
            hh, hl, Wqh + wo, Wql + wo, nullptr, nullptr, Qh, Ql,
            nullptr, nullptr, 0, ROWS, DM, DM, 0, 0, 0);
        mgemm<2, false, false, false, false><<<gFull, 256, 0, stream>>>(
            hh, hl, Wkh + wo, Wkl + wo, nullptr, nullptr, Kh, Kl,
            nullptr, nullptr, 0, ROWS, DM, DM, 0, 0, 0);
        mgemm<0, false, false, false, false><<<gFull, 256, 0, stream>>>(
            hh, hl, Wvh + wo, Wvl + wo, nullptr, nullptr, Vh, Vl,
            nullptr, nullptr, 0, ROWS, DM, DM, 0, 0, 0);

        transpose_plane<<<gTr, 256, 0, stream>>>(Kh, Kth);
        transpose_plane<<<gTr, 256, 0, stream>>>(Kl, Ktl);
        transpose_plane<<<gTr, 256, 0, stream>>>(Vh, Vth);
        transpose_plane<<<gTr, 256, 0, stream>>>(Vl, Vtl);

        // denominator path (before PV: AOUT epilogue reads den)
        zpart_kernel<<<dim3(NCH, NB), 256, 0, stream>>>(Kh, Kl, Zp);
        zprefix_kernel<<<NB, 256, 0, stream>>>(Zp);
        denom_kernel<<<128, 256, 0, stream>>>(Qh, Ql, Kh, Kl, Zp, den);

        // Gt[c][i,n] = sum_r V[r,i] K[r,n]  (A=Vt, B=Kt)
        mgemm<0, false, false, false, false><<<gChunk, 256, 0, stream>>>(
            Vth, Vtl, Kth, Ktl, nullptr, GtF, nullptr, nullptr,
            nullptr, nullptr, 0, DM, DM, RC, CS, CS, CS);
        gprefix_split<<<1024, 256, 0, stream>>>(GtF, Gth, Gtl);

        // numer = Q_c @ S_prev  (B = Gt planes); overwrites GtF buffer
        mgemm<0, false, false, false, false><<<gChunk, 256, 0, stream>>>(
            Qh, Ql, Gth, Gtl, nullptr, GtF, nullptr, nullptr,
            nullptr, nullptr, 0, RC, DM, DM, CS, CS, CS);
        // P = Q_c K_c^T (causal)
        mgemm<0, false, true, false, false><<<gChunk, 256, 0, stream>>>(
            Qh, Ql, Kh, Kl, nullptr, nullptr, Ph, Pl,
            nullptr, nullptr, 0, RC, RC, DM, CS, CS, CS);
        // xattn = (P @ V_c + numer)/den + h -> planes (reuse Kt buffers)
        mgemm<0, false, false, true, true><<<gChunk, 256, 0, stream>>>(
            Ph, Pl, Vth, Vtl, nullptr, GtF, Kth, Ktl,
            hF, den, 0, RC, DM, RC, CS, CS, CS);

        // FFN1: g1 = relu(xattn @ h1W^T + b1) -> planes (reuse Q plane bufs)
        mgemm<1, false, false, false, false><<<gFull, 256, 0, stream>>>(
            Kth, Ktl, W1h + wo, W1l + wo, h1b + (long)l * DM,
            nullptr, Qh, Ql, nullptr, nullptr, 0, ROWS, DM, DM, 0, 0, 0);
        // FFN2: h = h + g1 @ h2W^T + b2  (fp32 + planes)
        mgemm<0, false, false, false, false><<<gFull, 256, 0, stream>>>(
            Qh, Ql, W2h + wo, W2l + wo, h2b + (long)l * DM,
            hF, hh, hl, hF, nullptr, 0, ROWS, DM, DM, 0, 0, 0);
    }

    // logits -> d_out, softmax in place
    mgemm<0, false, false, false, false><<<gOut, 256, 0, stream>>>(
        hh, hl, oWh, oWl, outb, out, nullptr, nullptr, nullptr, nullptr, 0,
        ROWS, DIO, DM, 0, 0, 0);
    softmax_kernel<<<ROWS / 4, 256, 0, stream>>>(out);
}